// Round 8
// baseline (205.997 us; speedup 1.0000x reference)
//
#include <hip/hip_runtime.h>

// Problem constants: A=1, B=8, M=256, H=2048, E=8, K=2, N=2048
#define Bn 8
#define Mn 256
#define Hn 2048
#define En 8
#define Kn 2
#define Nn 2048

typedef float vf4 __attribute__((ext_vector_type(4)));

// d_ws layout (floats):
//   hs  [Bn*Hn] 64 KB -- hidden column sums    (write-once, no init)
//   wsum[En*Hn] 64 KB -- gup row sums          (write-once, no init)
//
// R7 post-mortem: partial-table + 3rd dispatch regressed (+13us). Reverted to
// R6's 2-dispatch in-loop-shuffle structure. This round: PLAIN loads (no nt) --
// R2 measured FETCH=74MB for the 151MB stream, i.e. ~77MB was L3-resident;
// nontemporal loads forfeit those hits. Plus 8 rows/wave, prefetch distance 2.

// blocks [0, 128):   hidden full-column sums -> hs[b*Hn + k].
// blocks [128, 640): gup row sums. 2048 waves, wave w owns rows [8w, 8w+8).
//                    Distance-2 prefetch: refill row j+2 right after consuming
//                    row j, before the shuffle chain (chain hides load latency).
__global__ void reduce_kernel(const float* __restrict__ hidden,
                              const float* __restrict__ gup,
                              float* __restrict__ hs,
                              float* __restrict__ wsum) {
    const int bid = blockIdx.x;
    const int t   = threadIdx.x;
    if (bid < 128) {
        const int b   = bid >> 4;
        const int kh  = bid & 15;
        const int col = t & 31;          // float4 column within 128-float slice
        const int mg  = t >> 5;          // m-group: 32 rows each
        const vf4* hp = (const vf4*)(hidden + ((size_t)b * Mn + mg * 32) * Hn)
                        + kh * 32 + col;
        vf4 a0 = 0.f, a1 = 0.f, a2 = 0.f, a3 = 0.f;
#pragma unroll
        for (int m = 0; m < 32; m += 4) {
            vf4 v0 = hp[(size_t)(m + 0) * (Hn / 4)];
            vf4 v1 = hp[(size_t)(m + 1) * (Hn / 4)];
            vf4 v2 = hp[(size_t)(m + 2) * (Hn / 4)];
            vf4 v3 = hp[(size_t)(m + 3) * (Hn / 4)];
            a0 += v0; a1 += v1; a2 += v2; a3 += v3;
        }
        vf4 s = (a0 + a1) + (a2 + a3);
        __shared__ vf4 sd[8][32];
        sd[mg][col] = s;
        __syncthreads();
        if (t < 32) {
            vf4 r = sd[0][t];
#pragma unroll
            for (int g = 1; g < 8; ++g) r += sd[g][t];
            ((vf4*)hs)[(size_t)b * (Hn / 4) + kh * 32 + t] = r;
        }
    } else {
        const int wave = (bid - 128) * 4 + (t >> 6);   // 0..2047
        const int lane = t & 63;
        const size_t r0 = (size_t)wave * 8;            // first of 8 rows
        const vf4* base = (const vf4*)gup + r0 * (Nn / 4) + lane;
        vf4 buf[2][8];
#pragma unroll
        for (int i = 0; i < 8; ++i) buf[0][i] = base[0 * (Nn / 4) + i * 64];
#pragma unroll
        for (int i = 0; i < 8; ++i) buf[1][i] = base[1 * (Nn / 4) + i * 64];
        float rs[8];
#pragma unroll
        for (int j = 0; j < 8; ++j) {
            vf4* cur = buf[j & 1];
            vf4 v = ((cur[0] + cur[1]) + (cur[2] + cur[3]))
                  + ((cur[4] + cur[5]) + (cur[6] + cur[7]));
            float s = (v.x + v.y) + (v.z + v.w);
            if (j < 6) {
#pragma unroll
                for (int i = 0; i < 8; ++i)            // refill with row j+2
                    cur[i] = base[(size_t)(j + 2) * (Nn / 4) + i * 64];
            }
            // shuffle chain overlaps the refill's load latency
#pragma unroll
            for (int off = 32; off > 0; off >>= 1)
                s += __shfl_down(s, off, 64);
            rs[j] = s;                                 // valid on lane 0
        }
        if (lane == 0) {
            vf4 o0 = { rs[0], rs[1], rs[2], rs[3] };
            vf4 o1 = { rs[4], rs[5], rs[6], rs[7] };
            ((vf4*)wsum)[wave * 2]     = o0;           // rows 8w..8w+7 contiguous
            ((vf4*)wsum)[wave * 2 + 1] = o1;
        }
    }
}

// out = sum_{b,e,k} sp[b,e] * hs[b,k] * wsum[e,k]   (single block, 256 threads,
// reads only 128 KB)
__global__ void final_kernel(const float* __restrict__ sparsity,
                             const float* __restrict__ hs,
                             const float* __restrict__ wsum,
                             float* __restrict__ out) {
    __shared__ float sp[Bn][En];
    __shared__ float red[4];
    const int t = threadIdx.x;
    if (t < Bn * En) {
        const int b = t >> 3, e = t & 7;
        sp[b][e] = sparsity[b * (Kn * En) + e];   // sparsity[0, b, 0, e]
    }
    __syncthreads();
    float acc = 0.f;
#pragma unroll
    for (int i = 0; i < Hn / 256; ++i) {
        const int k = i * 256 + t;
        float h[Bn];
#pragma unroll
        for (int b = 0; b < Bn; ++b) h[b] = hs[b * Hn + k];
#pragma unroll
        for (int e = 0; e < En; ++e) {
            float g = 0.f;
#pragma unroll
            for (int b = 0; b < Bn; ++b) g += sp[b][e] * h[b];
            acc += wsum[e * Hn + k] * g;
        }
    }
#pragma unroll
    for (int off = 32; off > 0; off >>= 1)
        acc += __shfl_down(acc, off, 64);
    const int lane = t & 63, wave = t >> 6;
    if (lane == 0) red[wave] = acc;
    __syncthreads();
    if (t == 0) out[0] = (red[0] + red[1]) + (red[2] + red[3]);
}

extern "C" void kernel_launch(void* const* d_in, const int* in_sizes, int n_in,
                              void* d_out, int out_size, void* d_ws, size_t ws_size,
                              hipStream_t stream) {
    const float* hidden   = (const float*)d_in[0];  // (1,8,256,2048) fp32
    const float* sparsity = (const float*)d_in[1];  // (1,8,2,8) fp32
    const float* gup      = (const float*)d_in[2];  // (1,8,2048,2048) fp32

    float* hs   = (float*)d_ws;          // Bn*Hn floats (64 KB)
    float* wsum = hs + Bn * Hn;          // En*Hn floats (64 KB)

    reduce_kernel<<<128 + 512, 256, 0, stream>>>(hidden, gup, hs, wsum);
    final_kernel<<<1, 256, 0, stream>>>(sparsity, hs, wsum, (float*)d_out);
}

// Round 9
// 191.122 us; speedup vs baseline: 1.0778x; 1.0778x over previous
//
#include <hip/hip_runtime.h>

// Problem constants: A=1, B=8, M=256, H=2048, E=8, K=2, N=2048
#define Bn 8
#define Mn 256
#define Hn 2048
#define En 8
#define Kn 2
#define Nn 2048

typedef float vf4 __attribute__((ext_vector_type(4)));

// d_ws layout (floats):
//   hs  [Bn*Hn] 64 KB -- hidden column sums    (write-once, no init)
//   wsum[En*Hn] 64 KB -- gup row sums          (write-once, no init)
//
// Lineage: R6 (190 us, best) = nt loads + 4096 gup waves x 4 rows + dist-1
// prefetch. R7 (partial table, 3 dispatches) = 203. R8 (plain loads, 2048
// waves, dist-2) = 206. This round: EXACT R6 except pipeline deepened to
// distance-2 (rows 0,1 in flight before loop; refill j+2 right after row j's
// adds, before the shuffle chain). Single-variable test of per-row stall.

// blocks [0, 128):    hidden full-column sums -> hs[b*Hn + k]  (proven design).
// blocks [128, 1152): gup row sums, wave w owns rows [4w, 4w+4), dist-2 pipe.
__global__ void reduce_kernel(const float* __restrict__ hidden,
                              const float* __restrict__ gup,
                              float* __restrict__ hs,
                              float* __restrict__ wsum) {
    const int bid = blockIdx.x;
    const int t   = threadIdx.x;
    if (bid < 128) {
        const int b   = bid >> 4;
        const int kh  = bid & 15;
        const int col = t & 31;          // float4 column within 128-float slice
        const int mg  = t >> 5;          // m-group: 32 rows each
        const vf4* hp = (const vf4*)(hidden + ((size_t)b * Mn + mg * 32) * Hn)
                        + kh * 32 + col;
        vf4 a0 = 0.f, a1 = 0.f, a2 = 0.f, a3 = 0.f;
#pragma unroll
        for (int m = 0; m < 32; m += 4) {
            vf4 v0 = __builtin_nontemporal_load(hp + (size_t)(m + 0) * (Hn / 4));
            vf4 v1 = __builtin_nontemporal_load(hp + (size_t)(m + 1) * (Hn / 4));
            vf4 v2 = __builtin_nontemporal_load(hp + (size_t)(m + 2) * (Hn / 4));
            vf4 v3 = __builtin_nontemporal_load(hp + (size_t)(m + 3) * (Hn / 4));
            a0 += v0; a1 += v1; a2 += v2; a3 += v3;
        }
        vf4 s = (a0 + a1) + (a2 + a3);
        __shared__ vf4 sd[8][32];
        sd[mg][col] = s;
        __syncthreads();
        if (t < 32) {
            vf4 r = sd[0][t];
#pragma unroll
            for (int g = 1; g < 8; ++g) r += sd[g][t];
            ((vf4*)hs)[(size_t)b * (Hn / 4) + kh * 32 + t] = r;
        }
    } else {
        // 4096 waves; wave w handles rows [4w, 4w+4)
        const int wave = (bid - 128) * 4 + (t >> 6);
        const int lane = t & 63;
        const size_t r0 = (size_t)wave * 4;
        const vf4* base = (const vf4*)gup + r0 * (Nn / 4) + lane;
        vf4 buf[2][8];
#pragma unroll
        for (int i = 0; i < 8; ++i)
            buf[0][i] = __builtin_nontemporal_load(base + 0 * (Nn / 4) + i * 64);
#pragma unroll
        for (int i = 0; i < 8; ++i)
            buf[1][i] = __builtin_nontemporal_load(base + 1 * (Nn / 4) + i * 64);
        float rs[4];
#pragma unroll
        for (int j = 0; j < 4; ++j) {
            vf4* cur = buf[j & 1];
            vf4 v = ((cur[0] + cur[1]) + (cur[2] + cur[3]))
                  + ((cur[4] + cur[5]) + (cur[6] + cur[7]));
            float s = (v.x + v.y) + (v.z + v.w);
            if (j < 2) {
#pragma unroll
                for (int i = 0; i < 8; ++i)     // refill with row j+2 (dist-2)
                    cur[i] = __builtin_nontemporal_load(
                        base + (size_t)(j + 2) * (Nn / 4) + i * 64);
            }
            // shuffle chain overlaps the refill's load latency
#pragma unroll
            for (int off = 32; off > 0; off >>= 1)
                s += __shfl_down(s, off, 64);
            rs[j] = s;                          // valid on lane 0
        }
        if (lane == 0) {
            vf4 o = { rs[0], rs[1], rs[2], rs[3] };
            ((vf4*)wsum)[wave] = o;             // rows 4w..4w+3 contiguous
        }
    }
}

// out = sum_{b,e,k} sp[b,e] * hs[b,k] * wsum[e,k]   (single block, 256 threads,
// reads only 128 KB)
__global__ void final_kernel(const float* __restrict__ sparsity,
                             const float* __restrict__ hs,
                             const float* __restrict__ wsum,
                             float* __restrict__ out) {
    __shared__ float sp[Bn][En];
    __shared__ float red[4];
    const int t = threadIdx.x;
    if (t < Bn * En) {
        const int b = t >> 3, e = t & 7;
        sp[b][e] = sparsity[b * (Kn * En) + e];   // sparsity[0, b, 0, e]
    }
    __syncthreads();
    float acc = 0.f;
#pragma unroll
    for (int i = 0; i < Hn / 256; ++i) {
        const int k = i * 256 + t;
        float h[Bn];
#pragma unroll
        for (int b = 0; b < Bn; ++b) h[b] = hs[b * Hn + k];
#pragma unroll
        for (int e = 0; e < En; ++e) {
            float g = 0.f;
#pragma unroll
            for (int b = 0; b < Bn; ++b) g += sp[b][e] * h[b];
            acc += wsum[e * Hn + k] * g;
        }
    }
#pragma unroll
    for (int off = 32; off > 0; off >>= 1)
        acc += __shfl_down(acc, off, 64);
    const int lane = t & 63, wave = t >> 6;
    if (lane == 0) red[wave] = acc;
    __syncthreads();
    if (t == 0) out[0] = (red[0] + red[1]) + (red[2] + red[3]);
}

extern "C" void kernel_launch(void* const* d_in, const int* in_sizes, int n_in,
                              void* d_out, int out_size, void* d_ws, size_t ws_size,
                              hipStream_t stream) {
    const float* hidden   = (const float*)d_in[0];  // (1,8,256,2048) fp32
    const float* sparsity = (const float*)d_in[1];  // (1,8,2,8) fp32
    const float* gup      = (const float*)d_in[2];  // (1,8,2048,2048) fp32

    float* hs   = (float*)d_ws;          // Bn*Hn floats (64 KB)
    float* wsum = hs + Bn * Hn;          // En*Hn floats (64 KB)

    reduce_kernel<<<128 + 1024, 256, 0, stream>>>(hidden, gup, hs, wsum);
    final_kernel<<<1, 256, 0, stream>>>(sparsity, hs, wsum, (float*)d_out);
}